// Round 1
// baseline (1717.998 us; speedup 1.0000x reference)
//
#include <hip/hip_runtime.h>
#include <stdint.h>

#define B_ 8
#define L_ 4096
#define DM_ 1024
#define H_ 16
#define DH_ 64
#define U_ 45
#define BH_ 128
#define GROWS_ 384
#define GM_ 3072

typedef unsigned short u16;
typedef unsigned int u32;
typedef __attribute__((ext_vector_type(8))) short short8;
typedef __attribute__((ext_vector_type(4))) float f32x4;
typedef __attribute__((ext_vector_type(8))) float f32x8;

__device__ __forceinline__ u16 f2bf_rne(float x){
  u32 u = __float_as_uint(x);
  return (u16)((u + 0x7FFFu + ((u >> 16) & 1u)) >> 16);
}
__device__ __forceinline__ float bf2f(u16 v){ return __uint_as_float(((u32)v) << 16); }
__device__ __forceinline__ float bflo(u32 w){ return __uint_as_float(w << 16); }
__device__ __forceinline__ float bfhi(u32 w){ return __uint_as_float(w & 0xFFFF0000u); }

// async global->LDS, 16B per lane, wave-uniform LDS base + lane*16
__device__ __forceinline__ void gload_lds16(const void* g, void* l){
  auto gp = (const __attribute__((address_space(1))) u32*)(uintptr_t)g;
  auto lp = (__attribute__((address_space(3))) u32*)(u32)(uintptr_t)l;
  __builtin_amdgcn_global_load_lds(gp, lp, 16, 0, 0);
}

// ---------------- weight prep: fp32 -> bf16 hi (+ residual lo) ----------------
__device__ __forceinline__ void split1(float x, u16& h, u16& l){
  h = f2bf_rne(x);
  l = f2bf_rne(x - bf2f(h));
}

__global__ void prep_w(const float* __restrict__ Wq, const float* __restrict__ Wk,
                       const float* __restrict__ Wv,
                       u16* __restrict__ WQH, u16* __restrict__ WQL,
                       u16* __restrict__ WKH, u16* __restrict__ WKL,
                       u16* __restrict__ WVH){
  const int i = (blockIdx.x * 256 + threadIdx.x) * 4;
  float4 a; ushort4 h, l;
  a = *(const float4*)(Wq + i);
  split1(a.x, h.x, l.x); split1(a.y, h.y, l.y); split1(a.z, h.z, l.z); split1(a.w, h.w, l.w);
  *(ushort4*)(WQH + i) = h; *(ushort4*)(WQL + i) = l;
  a = *(const float4*)(Wk + i);
  split1(a.x, h.x, l.x); split1(a.y, h.y, l.y); split1(a.z, h.z, l.z); split1(a.w, h.w, l.w);
  *(ushort4*)(WKH + i) = h; *(ushort4*)(WKL + i) = l;
  a = *(const float4*)(Wv + i);
  split1(a.x, h.x, l.x); split1(a.y, h.y, l.y); split1(a.z, h.z, l.z); split1(a.w, h.w, l.w);
  *(ushort4*)(WVH + i) = h;
}

// ---------------- gather sampled K rows (fp32) ----------------
__global__ void gather_rows(const float* __restrict__ K, const int* __restrict__ IDX,
                            float* __restrict__ GATH){
  const int blk = blockIdx.x;           // 0..359
  const int b = blk / U_, u = blk % U_;
  const int t = threadIdx.x;
  const int row = IDX[u];
  const float4* src = (const float4*)(K + ((size_t)b * L_ + row) * DM_);
  float4* dst = (float4*)(GATH + ((size_t)(b * GROWS_ + u)) * DM_);
  dst[t] = src[t];
}

// ---------------- projection GEMM ----------------
// C[g, c] = sum_k A[g,k] * W[c,k] + bias[c]
// A fp32 [M x 1024] row-major, W bf16 hi(/lo) [1024 x 1024] row-major.
// PASSES=3: A split to hi/lo in-regs, 3 MFMAs (ah*bh + ah*bl + al*bh)  (~2^-16 rel err)
// OUTMODE 0: fp32 scatter to [B,H,L,64]; 1: bf16(trunc) scatter; 2: plain fp32 [M x 1024]
template<int PASSES, int OUTMODE>
__launch_bounds__(256, 2)
__global__ void gemm_proj(const float* __restrict__ A, const u16* __restrict__ BHp,
                          const u16* __restrict__ BLp, const float* __restrict__ bias,
                          void* __restrict__ outp){
  const int n0 = blockIdx.x * 128;
  const int m0 = blockIdx.y * 128;
  const int t = threadIdx.x;
  const int w = t >> 6, lane = t & 63;
  const int wr = w >> 1, wc = w & 1;

  __shared__ float As[128 * 64];                       // 32 KB
  __shared__ u16   Bhs[128 * 64];                      // 16 KB
  __shared__ u16   Bls[(PASSES == 3) ? (128 * 64) : 64];

  f32x4 acc[4][4];
#pragma unroll
  for (int i = 0; i < 4; i++)
#pragma unroll
    for (int j = 0; j < 4; j++) acc[i][j] = (f32x4){0.f, 0.f, 0.f, 0.f};

  const int arow = lane >> 4;            // 0..3
  const int acol = (lane & 15) * 4;      // floats
  const int brow = lane >> 3;            // 0..7
  const int bcol = (lane & 7) * 8;       // u16s

  for (int kt = 0; kt < 16; kt++){
    const int k0 = kt * 64;
    // stage A fp32 128x64 : 32 instrs x 1024B (4 rows each)
#pragma unroll
    for (int ii = 0; ii < 8; ii++){
      const int nn = w * 8 + ii;
      const float* gp = A + (size_t)(m0 + 4 * nn + arow) * DM_ + (k0 + acol);
      gload_lds16(gp, As + nn * 256);
    }
    // stage B bf16 128x64 : 16 instrs x 1024B (8 rows each)
#pragma unroll
    for (int ii = 0; ii < 4; ii++){
      const int nn = w * 4 + ii;
      const size_t go = (size_t)(n0 + 8 * nn + brow) * DM_ + (k0 + bcol);
      gload_lds16(BHp + go, Bhs + nn * 512);
      if constexpr (PASSES == 3) gload_lds16(BLp + go, Bls + nn * 512);
    }
    __syncthreads();

#pragma unroll
    for (int ks = 0; ks < 2; ks++){
      const int kk = ks * 32 + (lane >> 4) * 8;
      short8 ah[4], al[4];
#pragma unroll
      for (int i = 0; i < 4; i++){
        const float* ap = As + (wr * 64 + i * 16 + (lane & 15)) * 64 + kk;
        f32x8 x = *(const f32x8*)ap;
        short8 h, l;
#pragma unroll
        for (int c = 0; c < 8; c++){
          const u32 ub = __float_as_uint(x[c]);
          h[c] = (short)(ub >> 16);                       // truncation hi
          if constexpr (PASSES == 3){
            const float r = x[c] - __uint_as_float(ub & 0xFFFF0000u);  // exact residual
            l[c] = (short)(__float_as_uint(r) >> 16);
          }
        }
        ah[i] = h;
        if constexpr (PASSES == 3) al[i] = l;
      }
      short8 bh8[4], bl8[4];
#pragma unroll
      for (int j = 0; j < 4; j++){
        const int bo = (wc * 64 + j * 16 + (lane & 15)) * 64 + kk;
        bh8[j] = *(const short8*)(Bhs + bo);
        if constexpr (PASSES == 3) bl8[j] = *(const short8*)(Bls + bo);
      }
#pragma unroll
      for (int i = 0; i < 4; i++)
#pragma unroll
        for (int j = 0; j < 4; j++){
          acc[i][j] = __builtin_amdgcn_mfma_f32_16x16x32_bf16(ah[i], bh8[j], acc[i][j], 0, 0, 0);
          if constexpr (PASSES == 3){
            acc[i][j] = __builtin_amdgcn_mfma_f32_16x16x32_bf16(ah[i], bl8[j], acc[i][j], 0, 0, 0);
            acc[i][j] = __builtin_amdgcn_mfma_f32_16x16x32_bf16(al[i], bh8[j], acc[i][j], 0, 0, 0);
          }
        }
    }
    __syncthreads();
  }

  // epilogue: C/D layout col=lane&15, row=(lane>>4)*4+reg  [verified m89/m91]
#pragma unroll
  for (int j = 0; j < 4; j++){
    const int c = n0 + wc * 64 + j * 16 + (lane & 15);
    const float bv = bias[c];
#pragma unroll
    for (int i = 0; i < 4; i++){
      const int mb = m0 + wr * 64 + i * 16 + (lane >> 4) * 4;
#pragma unroll
      for (int r = 0; r < 4; r++){
        const int g = mb + r;
        const float val = acc[i][j][r] + bv;
        if constexpr (OUTMODE == 2){
          ((float*)outp)[(size_t)g * DM_ + c] = val;
        } else {
          const int b = g >> 12, l2 = g & 4095;
          const int h = c >> 6, d = c & 63;
          const size_t oi = (((size_t)(b * H_ + h)) * L_ + l2) * DH_ + d;
          if constexpr (OUTMODE == 0) ((float*)outp)[oi] = val;
          else ((u16*)outp)[oi] = (u16)(__float_as_uint(val) >> 16);
        }
      }
    }
  }
}

// ---------------- M = max_s(qk) - mean_s(qk) ----------------
__global__ void compute_m(const float* __restrict__ QF, const float* __restrict__ KSAMP,
                          float* __restrict__ MBUF){
  const int bx = blockIdx.x;
  const int bh = bx >> 4, lp = bx & 15;
  const int b = bh >> 4, h = bh & 15;
  const int t = threadIdx.x;
  __shared__ float ks[U_ * DH_];
  for (int i = t; i < U_ * DH_; i += 256){
    const int u = i >> 6, d = i & 63;
    ks[i] = KSAMP[((size_t)(b * GROWS_ + u)) * DM_ + h * DH_ + d];
  }
  __syncthreads();
  const int l = lp * 256 + t;
  const float* q = QF + ((size_t)bh * L_ + l) * DH_;
  float4 qv[16];
#pragma unroll
  for (int c = 0; c < 16; c++) qv[c] = *(const float4*)(q + c * 4);
  float mx = -1e30f, sm = 0.f;
  for (int u = 0; u < U_; u++){
    const float* kp = ks + u * 64;
    float acc = 0.f;
#pragma unroll
    for (int c = 0; c < 16; c++){
      const float4 kv = *(const float4*)(kp + c * 4);
      acc += qv[c].x * kv.x + qv[c].y * kv.y + qv[c].z * kv.z + qv[c].w * kv.w;
    }
    mx = fmaxf(mx, acc); sm += acc;
  }
  MBUF[(size_t)bh * L_ + l] = mx - sm * (1.0f / 45.0f);
}

// ---------------- iterative top-45 (lowest-index tie-break) ----------------
__global__ void topk45(const float* __restrict__ MBUF, int* __restrict__ MTOP){
  const int bh = blockIdx.x;
  const int t = threadIdx.x;
  __shared__ float Mv[L_];
  __shared__ float rv[256];
  __shared__ int ri[256];
  for (int i = t; i < L_; i += 256) Mv[i] = MBUF[(size_t)bh * L_ + i];
  __syncthreads();
  for (int it = 0; it < U_; it++){
    float bv = -1e30f; int bi = 0;
#pragma unroll
    for (int c = 0; c < 16; c++){
      const int idx = t * 16 + c;
      const float v = Mv[idx];
      if (v > bv){ bv = v; bi = idx; }
    }
    rv[t] = bv; ri[t] = bi;
    __syncthreads();
    for (int off = 128; off > 0; off >>= 1){
      if (t < off){
        const float v2 = rv[t + off]; const int i2 = ri[t + off];
        if (v2 > rv[t] || (v2 == rv[t] && i2 < ri[t])){ rv[t] = v2; ri[t] = i2; }
      }
      __syncthreads();
    }
    if (t == 0){ MTOP[bh * U_ + it] = ri[0]; Mv[ri[0]] = -1e30f; }
    __syncthreads();
  }
}

// ---------------- scores + full-row softmax (one block per (b,h,u)) ----------------
__global__ void s1_scores(const float* __restrict__ QF, const u16* __restrict__ KB,
                          const int* __restrict__ MTOP, u16* __restrict__ PBUF,
                          float* __restrict__ LBUF){
  const int blk = blockIdx.x;
  const int bh = blk / U_, u = blk % U_;
  const int t = threadIdx.x, w = t >> 6, lane = t & 63;
  __shared__ float q[64];
  __shared__ float red[4];
  __shared__ float red2[4];
  if (t < 64){
    const int qrow = MTOP[bh * U_ + u];
    q[t] = QF[((size_t)bh * L_ + qrow) * DH_ + t];
  }
  __syncthreads();
  const u16* kb = KB + (size_t)bh * L_ * DH_;
  const int j0 = t * 16;
  float s[16];
#pragma unroll 2
  for (int jj = 0; jj < 16; jj++){
    const u32* kr = (const u32*)(kb + (size_t)(j0 + jj) * DH_);
    float acc = 0.f;
#pragma unroll
    for (int c = 0; c < 8; c++){
      const uint4 pk = *(const uint4*)(kr + c * 4);
      acc += q[c*8+0]*bflo(pk.x) + q[c*8+1]*bfhi(pk.x)
           + q[c*8+2]*bflo(pk.y) + q[c*8+3]*bfhi(pk.y)
           + q[c*8+4]*bflo(pk.z) + q[c*8+5]*bfhi(pk.z)
           + q[c*8+6]*bflo(pk.w) + q[c*8+7]*bfhi(pk.w);
    }
    s[jj] = acc * 0.125f;   // 1/sqrt(64)
  }
  float m = -1e30f;
#pragma unroll
  for (int jj = 0; jj < 16; jj++) m = fmaxf(m, s[jj]);
  for (int off = 32; off > 0; off >>= 1) m = fmaxf(m, __shfl_xor(m, off));
  if (lane == 0) red[w] = m;
  __syncthreads();
  m = fmaxf(fmaxf(red[0], red[1]), fmaxf(red[2], red[3]));
  float lsum = 0.f;
  u16 pb[16];
#pragma unroll
  for (int jj = 0; jj < 16; jj++){
    const float pv = __expf(s[jj] - m);
    const u16 pq = f2bf_rne(pv);
    pb[jj] = pq;
    lsum += bf2f(pq);        // l consistent with stored (rounded) p
  }
  for (int off = 32; off > 0; off >>= 1) lsum += __shfl_xor(lsum, off);
  if (lane == 0) red2[w] = lsum;
  __syncthreads();
  u32 pw[8];
#pragma unroll
  for (int c = 0; c < 8; c++) pw[c] = (u32)pb[2 * c] | ((u32)pb[2 * c + 1] << 16);
  u32* pp = (u32*)(PBUF + (size_t)(bh * U_ + u) * L_ + j0);
  *(uint4*)pp       = make_uint4(pw[0], pw[1], pw[2], pw[3]);
  *((uint4*)pp + 1) = make_uint4(pw[4], pw[5], pw[6], pw[7]);
  if (t == 0) LBUF[bh * U_ + u] = red2[0] + red2[1] + red2[2] + red2[3];
}

// ---------------- PV: ctx[bh,u,d] = sum_j p*v / l ----------------
__global__ void s2_pv(const u16* __restrict__ VB, const u16* __restrict__ PBUF,
                      const float* __restrict__ LBUF, float* __restrict__ CTX){
  const int blk = blockIdx.x;
  const int bh = blk / U_, u = blk % U_;
  const int t = threadIdx.x;
  const int d = t & 63, jc = t >> 6;
  const u16* pr = PBUF + (size_t)(bh * U_ + u) * L_ + jc * 1024;
  const u16* vp = VB + (size_t)bh * L_ * DH_ + (size_t)jc * 1024 * DH_ + d;
  float acc = 0.f;
#pragma unroll 8
  for (int j = 0; j < 1024; j++){
    acc += bf2f(pr[j]) * bf2f(vp[(size_t)j * DH_]);
  }
  __shared__ float r[4][64];
  r[jc][d] = acc;
  __syncthreads();
  if (t < 64){
    const float sv = r[0][t] + r[1][t] + r[2][t] + r[3][t];
    CTX[(size_t)(bh * U_ + u) * DH_ + t] = sv / LBUF[bh * U_ + u];
  }
}

// ---------------- mean over u, write ctx_flat[b, d*16+h] ----------------
__global__ void s3_mean(const float* __restrict__ CTX, float* __restrict__ CTXF){
  const int bh = blockIdx.x;
  const int b = bh >> 4, h = bh & 15;
  const int d = threadIdx.x;   // 64
  float a = 0.f;
  for (int u = 0; u < U_; u++) a += CTX[(size_t)(bh * U_ + u) * DH_ + d];
  CTXF[b * DM_ + d * H_ + h] = a * (1.0f / 45.0f);
}

// ---------------- out[b,j] = ctx_flat[b] . Wo[j,:] + bo[j] ----------------
__global__ void s4_out(const float* __restrict__ CTXF, const float* __restrict__ Wo,
                       const float* __restrict__ bo, float* __restrict__ out){
  const int jb = blockIdx.x;   // 4
  const int b = blockIdx.y;    // 8
  const int t = threadIdx.x;
  __shared__ float cx[DM_];
  for (int i = t; i < DM_; i += 256) cx[i] = CTXF[b * DM_ + i];
  __syncthreads();
  const int j = jb * 256 + t;
  const float* wrow = Wo + (size_t)j * DM_;
  float acc = bo[j];
  for (int c = 0; c < 256; c++){
    const float4 wv = *(const float4*)(wrow + c * 4);
    const float4 cv = *(const float4*)(cx + c * 4);
    acc += wv.x * cv.x + wv.y * cv.y + wv.z * cv.z + wv.w * cv.w;
  }
  out[b * DM_ + j] = acc;
}

extern "C" void kernel_launch(void* const* d_in, const int* in_sizes, int n_in,
                              void* d_out, int out_size, void* d_ws, size_t ws_size,
                              hipStream_t stream){
  const float* Q  = (const float*)d_in[0];
  const float* K  = (const float*)d_in[1];
  const float* V  = (const float*)d_in[2];
  const float* Wq = (const float*)d_in[3];
  const float* bq = (const float*)d_in[4];
  const float* Wk = (const float*)d_in[5];
  const float* bk = (const float*)d_in[6];
  const float* Wv = (const float*)d_in[7];
  const float* bv = (const float*)d_in[8];
  const float* Wo = (const float*)d_in[9];
  const float* bo = (const float*)d_in[10];
  const int* IDX  = (const int*)d_in[11];
  float* out = (float*)d_out;

  char* p = (char*)d_ws;
  auto alloc = [&](size_t bytes) -> char* {
    char* r = p; p += (bytes + 255) & ~(size_t)255; return r;
  };
  u16*  WQH  = (u16*)alloc((size_t)DM_ * DM_ * 2);
  u16*  WQL  = (u16*)alloc((size_t)DM_ * DM_ * 2);
  u16*  WKH  = (u16*)alloc((size_t)DM_ * DM_ * 2);
  u16*  WKL  = (u16*)alloc((size_t)DM_ * DM_ * 2);
  u16*  WVH  = (u16*)alloc((size_t)DM_ * DM_ * 2);
  float* QF  = (float*)alloc((size_t)BH_ * L_ * DH_ * 4);   // 128 MiB
  u16*  KB   = (u16*)alloc((size_t)BH_ * L_ * DH_ * 2);     // 64 MiB
  u16*  VB   = (u16*)alloc((size_t)BH_ * L_ * DH_ * 2);     // 64 MiB
  float* GATH = (float*)alloc((size_t)GM_ * DM_ * 4);       // 12 MiB
  float* KSAMP= (float*)alloc((size_t)GM_ * DM_ * 4);       // 12 MiB
  float* MBUF = (float*)alloc((size_t)BH_ * L_ * 4);        // 2 MiB
  int*   MTOP = (int*)alloc((size_t)BH_ * U_ * 4);
  u16*  PBUF  = (u16*)alloc((size_t)BH_ * U_ * L_ * 2);     // 45 MiB
  float* LBUF = (float*)alloc((size_t)BH_ * U_ * 4);
  float* CTX  = (float*)alloc((size_t)BH_ * U_ * DH_ * 4);
  float* CTXF = (float*)alloc((size_t)B_ * DM_ * 4);

  prep_w<<<dim3(1024), dim3(256), 0, stream>>>(Wq, Wk, Wv, WQH, WQL, WKH, WKL, WVH);
  gather_rows<<<dim3(B_ * U_), dim3(256), 0, stream>>>(K, IDX, GATH);
  gemm_proj<3, 0><<<dim3(8, 256), dim3(256), 0, stream>>>(Q, WQH, WQL, bq, (void*)QF);
  gemm_proj<1, 1><<<dim3(8, 256), dim3(256), 0, stream>>>(K, WKH, (const u16*)nullptr, bk, (void*)KB);
  gemm_proj<1, 1><<<dim3(8, 256), dim3(256), 0, stream>>>(V, WVH, (const u16*)nullptr, bv, (void*)VB);
  gemm_proj<3, 2><<<dim3(8, GM_ / 128), dim3(256), 0, stream>>>(GATH, WKH, WKL, bk, (void*)KSAMP);
  compute_m<<<dim3(BH_ * 16), dim3(256), 0, stream>>>(QF, KSAMP, MBUF);
  topk45<<<dim3(BH_), dim3(256), 0, stream>>>(MBUF, MTOP);
  s1_scores<<<dim3(BH_ * U_), dim3(256), 0, stream>>>(QF, KB, MTOP, PBUF, LBUF);
  s2_pv<<<dim3(BH_ * U_), dim3(256), 0, stream>>>(VB, PBUF, LBUF, CTX);
  s3_mean<<<dim3(BH_), dim3(64), 0, stream>>>(CTX, CTXF);
  s4_out<<<dim3(4, 8), dim3(256), 0, stream>>>(CTXF, Wo, bo, out);
}

// Round 2
// 1186.896 us; speedup vs baseline: 1.4475x; 1.4475x over previous
//
#include <hip/hip_runtime.h>
#include <stdint.h>

#define B_ 8
#define L_ 4096
#define DM_ 1024
#define H_ 16
#define DH_ 64
#define U_ 45
#define BH_ 128
#define GROWS_ 384
#define GM_ 3072
#define CHUNKS_ 2

typedef unsigned short u16;
typedef unsigned int u32;
typedef __attribute__((ext_vector_type(8))) short short8;
typedef __attribute__((ext_vector_type(4))) float f32x4;
typedef __attribute__((ext_vector_type(8))) float f32x8;

__device__ __forceinline__ u16 f2bf_rne(float x){
  u32 u = __float_as_uint(x);
  return (u16)((u + 0x7FFFu + ((u >> 16) & 1u)) >> 16);
}
__device__ __forceinline__ float bf2f(u16 v){ return __uint_as_float(((u32)v) << 16); }

// async global->LDS, 16B per lane, wave-uniform LDS base + lane*16
__device__ __forceinline__ void gload_lds16(const void* g, void* l){
  auto gp = (const __attribute__((address_space(1))) u32*)(uintptr_t)g;
  auto lp = (__attribute__((address_space(3))) u32*)(u32)(uintptr_t)l;
  __builtin_amdgcn_global_load_lds(gp, lp, 16, 0, 0);
}

// ---------------- weight prep: fp32 -> bf16 hi (+ residual lo) ----------------
__device__ __forceinline__ void split1(float x, u16& h, u16& l){
  h = f2bf_rne(x);
  l = f2bf_rne(x - bf2f(h));
}

__global__ void prep_w(const float* __restrict__ Wq, const float* __restrict__ Wk,
                       const float* __restrict__ Wv,
                       u16* __restrict__ WQH, u16* __restrict__ WQL,
                       u16* __restrict__ WKH, u16* __restrict__ WKL,
                       u16* __restrict__ WVH){
  const int i = (blockIdx.x * 256 + threadIdx.x) * 4;
  float4 a; ushort4 h, l;
  a = *(const float4*)(Wq + i);
  split1(a.x, h.x, l.x); split1(a.y, h.y, l.y); split1(a.z, h.z, l.z); split1(a.w, h.w, l.w);
  *(ushort4*)(WQH + i) = h; *(ushort4*)(WQL + i) = l;
  a = *(const float4*)(Wk + i);
  split1(a.x, h.x, l.x); split1(a.y, h.y, l.y); split1(a.z, h.z, l.z); split1(a.w, h.w, l.w);
  *(ushort4*)(WKH + i) = h; *(ushort4*)(WKL + i) = l;
  a = *(const float4*)(Wv + i);
  split1(a.x, h.x, l.x); split1(a.y, h.y, l.y); split1(a.z, h.z, l.z); split1(a.w, h.w, l.w);
  *(ushort4*)(WVH + i) = h;
}

// ---------------- gather sampled K rows (fp32) ----------------
__global__ void gather_rows(const float* __restrict__ K, const int* __restrict__ IDX,
                            float* __restrict__ GATH){
  const int blk = blockIdx.x;           // 0..359
  const int b = blk / U_, u = blk % U_;
  const int t = threadIdx.x;
  const int row = IDX[u];
  const float4* src = (const float4*)(K + ((size_t)b * L_ + row) * DM_);
  float4* dst = (float4*)(GATH + ((size_t)(b * GROWS_ + u)) * DM_);
  dst[t] = src[t];
}

// ---------------- projection GEMM ----------------
// C[g, c] = sum_k A[g,k] * W[c,k] + bias[c]
// A fp32 [M x 1024] row-major, W bf16 hi(/lo) [1024 x 1024] row-major.
// PASSES=3: A split to hi/lo in-regs, 3 MFMAs (ah*bh + ah*bl + al*bh)  (~2^-16 rel err)
// OUTMODE 0: fp32 scatter [B,H,L,64]; 1: bf16 scatter [B,H,L,64];
// OUTMODE 2: fp32 [M x 1024]; 3: bf16 transposed [B,H,64,L] via LDS transpose
template<int PASSES, int OUTMODE>
__launch_bounds__(256, 2)
__global__ void gemm_proj(const float* __restrict__ A, const u16* __restrict__ BHp,
                          const u16* __restrict__ BLp, const float* __restrict__ bias,
                          void* __restrict__ outp){
  const int n0 = blockIdx.x * 128;
  const int m0 = blockIdx.y * 128;
  const int t = threadIdx.x;
  const int w = t >> 6, lane = t & 63;
  const int wr = w >> 1, wc = w & 1;

  __shared__ __attribute__((aligned(16))) float As[128 * 64];   // 32 KB
  __shared__ __attribute__((aligned(16))) u16   Bhs[128 * 64];  // 16 KB
  __shared__ __attribute__((aligned(16))) u16   Bls[(PASSES == 3) ? (128 * 64) : 64];

  f32x4 acc[4][4];
#pragma unroll
  for (int i = 0; i < 4; i++)
#pragma unroll
    for (int j = 0; j < 4; j++) acc[i][j] = (f32x4){0.f, 0.f, 0.f, 0.f};

  const int arow = lane >> 4;            // 0..3
  const int acol = (lane & 15) * 4;      // floats
  const int brow = lane >> 3;            // 0..7
  const int bcol = (lane & 7) * 8;       // u16s

  for (int kt = 0; kt < 16; kt++){
    const int k0 = kt * 64;
#pragma unroll
    for (int ii = 0; ii < 8; ii++){
      const int nn = w * 8 + ii;
      const float* gp = A + (size_t)(m0 + 4 * nn + arow) * DM_ + (k0 + acol);
      gload_lds16(gp, As + nn * 256);
    }
#pragma unroll
    for (int ii = 0; ii < 4; ii++){
      const int nn = w * 4 + ii;
      const size_t go = (size_t)(n0 + 8 * nn + brow) * DM_ + (k0 + bcol);
      gload_lds16(BHp + go, Bhs + nn * 512);
      if constexpr (PASSES == 3) gload_lds16(BLp + go, Bls + nn * 512);
    }
    __syncthreads();

#pragma unroll
    for (int ks = 0; ks < 2; ks++){
      const int kk = ks * 32 + (lane >> 4) * 8;
      short8 ah[4], al[4];
#pragma unroll
      for (int i = 0; i < 4; i++){
        const float* ap = As + (wr * 64 + i * 16 + (lane & 15)) * 64 + kk;
        f32x8 x = *(const f32x8*)ap;
        short8 h, l;
#pragma unroll
        for (int c = 0; c < 8; c++){
          const u32 ub = __float_as_uint(x[c]);
          h[c] = (short)(ub >> 16);
          if constexpr (PASSES == 3){
            const float r = x[c] - __uint_as_float(ub & 0xFFFF0000u);
            l[c] = (short)(__float_as_uint(r) >> 16);
          }
        }
        ah[i] = h;
        if constexpr (PASSES == 3) al[i] = l;
      }
      short8 bh8[4], bl8[4];
#pragma unroll
      for (int j = 0; j < 4; j++){
        const int bo = (wc * 64 + j * 16 + (lane & 15)) * 64 + kk;
        bh8[j] = *(const short8*)(Bhs + bo);
        if constexpr (PASSES == 3) bl8[j] = *(const short8*)(Bls + bo);
      }
#pragma unroll
      for (int i = 0; i < 4; i++)
#pragma unroll
        for (int j = 0; j < 4; j++){
          acc[i][j] = __builtin_amdgcn_mfma_f32_16x16x32_bf16(ah[i], bh8[j], acc[i][j], 0, 0, 0);
          if constexpr (PASSES == 3){
            acc[i][j] = __builtin_amdgcn_mfma_f32_16x16x32_bf16(ah[i], bl8[j], acc[i][j], 0, 0, 0);
            acc[i][j] = __builtin_amdgcn_mfma_f32_16x16x32_bf16(al[i], bh8[j], acc[i][j], 0, 0, 0);
          }
        }
    }
    __syncthreads();
  }

  // epilogue: C/D layout col=lane&15, row=(lane>>4)*4+reg  [verified m89/m91]
  if constexpr (OUTMODE == 3){
    // transposed bf16 out: VT[((b*16+h)*64+d) * 4096 + l], coalesced via LDS transpose
    u16* tb = (u16*)As;                  // 64 x 136 u16 = 17408 B, reuses As
    const int b = m0 >> 12;
    const int l0 = m0 & 4095;
#pragma unroll
    for (int p = 0; p < 2; p++){
      if (wc == p){
#pragma unroll
        for (int j = 0; j < 4; j++){
          const int cl = j * 16 + (lane & 15);
          const float bv = bias[n0 + p * 64 + cl];
#pragma unroll
          for (int i = 0; i < 4; i++){
#pragma unroll
            for (int r = 0; r < 4; r++){
              const int gl = wr * 64 + i * 16 + (lane >> 4) * 4 + r;
              tb[cl * 136 + gl] = f2bf_rne(acc[i][j][r] + bv);
            }
          }
        }
      }
      __syncthreads();
      // store: 64 c-rows x 128 l, 16B chunks
      {
        const int cl = t >> 2;                    // 0..63
        const int c = n0 + p * 64 + cl;
        const int h = c >> 6, d = c & 63;
        u16* dst = (u16*)outp + ((size_t)((b * H_ + h) * DH_ + d)) * L_ + l0;
#pragma unroll
        for (int k = 0; k < 4; k++){
          const int ch = (t & 3) + k * 4;         // 0..15
          *(short8*)(dst + ch * 8) = *(const short8*)(tb + cl * 136 + ch * 8);
        }
      }
      __syncthreads();
    }
  } else {
#pragma unroll
    for (int j = 0; j < 4; j++){
      const int c = n0 + wc * 64 + j * 16 + (lane & 15);
      const float bv = bias[c];
#pragma unroll
      for (int i = 0; i < 4; i++){
        const int mb = m0 + wr * 64 + i * 16 + (lane >> 4) * 4;
#pragma unroll
        for (int r = 0; r < 4; r++){
          const int g = mb + r;
          const float val = acc[i][j][r] + bv;
          if constexpr (OUTMODE == 2){
            ((float*)outp)[(size_t)g * DM_ + c] = val;
          } else {
            const int b = g >> 12, l2 = g & 4095;
            const int h = c >> 6, d = c & 63;
            const size_t oi = (((size_t)(b * H_ + h)) * L_ + l2) * DH_ + d;
            if constexpr (OUTMODE == 0) ((float*)outp)[oi] = val;
            else ((u16*)outp)[oi] = (u16)(__float_as_uint(val) >> 16);
          }
        }
      }
    }
  }
}

// ---------------- M = max_s(qk) - mean_s(qk) ----------------
__global__ void compute_m(const float* __restrict__ QF, const float* __restrict__ KSAMP,
                          float* __restrict__ MBUF){
  const int bx = blockIdx.x;
  const int bh = bx >> 4, lp = bx & 15;
  const int b = bh >> 4, h = bh & 15;
  const int t = threadIdx.x;
  __shared__ float ks[U_ * DH_];
  for (int i = t; i < U_ * DH_; i += 256){
    const int u = i >> 6, d = i & 63;
    ks[i] = KSAMP[((size_t)(b * GROWS_ + u)) * DM_ + h * DH_ + d];
  }
  __syncthreads();
  const int l = lp * 256 + t;
  const float* q = QF + ((size_t)bh * L_ + l) * DH_;
  float4 qv[16];
#pragma unroll
  for (int c = 0; c < 16; c++) qv[c] = *(const float4*)(q + c * 4);
  float mx = -1e30f, sm = 0.f;
  for (int u = 0; u < U_; u++){
    const float* kp = ks + u * 64;
    float acc = 0.f;
#pragma unroll
    for (int c = 0; c < 16; c++){
      const float4 kv = *(const float4*)(kp + c * 4);
      acc += qv[c].x * kv.x + qv[c].y * kv.y + qv[c].z * kv.z + qv[c].w * kv.w;
    }
    mx = fmaxf(mx, acc); sm += acc;
  }
  MBUF[(size_t)bh * L_ + l] = mx - sm * (1.0f / 45.0f);
}

// ---------------- iterative top-45 (lowest-index tie-break) ----------------
__global__ void topk45(const float* __restrict__ MBUF, int* __restrict__ MTOP){
  const int bh = blockIdx.x;
  const int t = threadIdx.x;
  __shared__ float Mv[L_];
  __shared__ float rv[256];
  __shared__ int ri[256];
  for (int i = t; i < L_; i += 256) Mv[i] = MBUF[(size_t)bh * L_ + i];
  __syncthreads();
  for (int it = 0; it < U_; it++){
    float bv = -1e30f; int bi = 0;
#pragma unroll
    for (int c = 0; c < 16; c++){
      const int idx = t * 16 + c;
      const float v = Mv[idx];
      if (v > bv){ bv = v; bi = idx; }
    }
    rv[t] = bv; ri[t] = bi;
    __syncthreads();
    for (int off = 128; off > 0; off >>= 1){
      if (t < off){
        const float v2 = rv[t + off]; const int i2 = ri[t + off];
        if (v2 > rv[t] || (v2 == rv[t] && i2 < ri[t])){ rv[t] = v2; ri[t] = i2; }
      }
      __syncthreads();
    }
    if (t == 0){ MTOP[bh * U_ + it] = ri[0]; Mv[ri[0]] = -1e30f; }
    __syncthreads();
  }
}

// ---------------- fused flash-style attention (MFMA) ----------------
// Per (bh, chunk): 4 waves, each owns a disjoint K-range with private online
// softmax state (m,l,O). Partials to MLP/CTXP; attn_combine merges.
__launch_bounds__(256, 2)
__global__ void attn_fused(const float* __restrict__ QF, const u16* __restrict__ KB,
                           const u16* __restrict__ VT, const int* __restrict__ MTOP,
                           float* __restrict__ MLP, float* __restrict__ CTXP){
  const int bh = blockIdx.x;
  const int chunk = blockIdx.y;
  const int t = threadIdx.x, w = t >> 6, lane = t & 63;
  const int m16 = lane & 15, q4 = lane >> 4;

  __shared__ __attribute__((aligned(16))) float qs[48 * 68];     // padded stride
  __shared__ __attribute__((aligned(16))) u16 ps[4][48 * 72];    // per-wave P buf

  // load q_red (scaled by 1/sqrt(64)), rows 45..47 zero
  for (int i = t; i < 48 * 64; i += 256){
    const int r = i >> 6, d = i & 63;
    float v = 0.f;
    if (r < U_) v = QF[((size_t)bh * L_ + MTOP[bh * U_ + r]) * DH_ + d] * 0.125f;
    qs[r * 68 + d] = v;
  }
  __syncthreads();

  // q fragments (hi/lo split), A-layout: m=lane&15, k=ks*32+q4*8+j
  short8 qh[3][2], ql[3][2];
#pragma unroll
  for (int i = 0; i < 3; i++)
#pragma unroll
    for (int ks = 0; ks < 2; ks++){
      const float* ap = qs + (i * 16 + m16) * 68 + ks * 32 + q4 * 8;
      f32x8 x = *(const f32x8*)ap;
      short8 h, l;
#pragma unroll
      for (int c = 0; c < 8; c++){
        const u32 ub = __float_as_uint(x[c]);
        h[c] = (short)(ub >> 16);
        const float r = x[c] - __uint_as_float(ub & 0xFFFF0000u);
        l[c] = (short)(__float_as_uint(r) >> 16);
      }
      qh[i][ks] = h; ql[i][ks] = l;
    }

  float m_run[3][4], l_run[3][4];
  f32x4 O[3][4];
#pragma unroll
  for (int i = 0; i < 3; i++)
#pragma unroll
    for (int r = 0; r < 4; r++){
      m_run[i][r] = -1e30f; l_run[i][r] = 0.f;
      O[i][r] = (f32x4){0.f, 0.f, 0.f, 0.f};
    }

  const u16* kb = KB + (size_t)bh * L_ * DH_;
  const u16* vt = VT + (size_t)bh * DH_ * L_;
  const int TPW = L_ / (CHUNKS_ * 4 * 64);     // 8 tiles per wave
  u16* pw = ps[w];

  for (int tt = 0; tt < TPW; tt++){
    const int t0 = ((chunk * 4 + w) * TPW + tt) * 64;
    // S = q @ K^T (scaled), 48x64 tile
    f32x4 S[3][4];
#pragma unroll
    for (int i = 0; i < 3; i++)
#pragma unroll
      for (int jt = 0; jt < 4; jt++) S[i][jt] = (f32x4){0.f, 0.f, 0.f, 0.f};
#pragma unroll
    for (int ks = 0; ks < 2; ks++){
      short8 kf[4];
#pragma unroll
      for (int jt = 0; jt < 4; jt++)
        kf[jt] = *(const short8*)(kb + (size_t)(t0 + jt * 16 + m16) * DH_ + ks * 32 + q4 * 8);
#pragma unroll
      for (int i = 0; i < 3; i++)
#pragma unroll
        for (int jt = 0; jt < 4; jt++){
          S[i][jt] = __builtin_amdgcn_mfma_f32_16x16x32_bf16(qh[i][ks], kf[jt], S[i][jt], 0, 0, 0);
          S[i][jt] = __builtin_amdgcn_mfma_f32_16x16x32_bf16(ql[i][ks], kf[jt], S[i][jt], 0, 0, 0);
        }
    }
    // online softmax; C layout: row=i*16+q4*4+r, col=jt*16+m16
#pragma unroll
    for (int i = 0; i < 3; i++){
      float mnew[4], alpha[4], psum[4];
#pragma unroll
      for (int r = 0; r < 4; r++){
        float mx = fmaxf(fmaxf(S[i][0][r], S[i][1][r]), fmaxf(S[i][2][r], S[i][3][r]));
        mx = fmaxf(mx, __shfl_xor(mx, 1));
        mx = fmaxf(mx, __shfl_xor(mx, 2));
        mx = fmaxf(mx, __shfl_xor(mx, 4));
        mx = fmaxf(mx, __shfl_xor(mx, 8));
        mnew[r] = fmaxf(m_run[i][r], mx);
        alpha[r] = __expf(m_run[i][r] - mnew[r]);
        m_run[i][r] = mnew[r];
        l_run[i][r] *= alpha[r];
        psum[r] = 0.f;
      }
#pragma unroll
      for (int jo = 0; jo < 4; jo++)
#pragma unroll
        for (int r = 0; r < 4; r++) O[i][jo][r] *= alpha[r];
#pragma unroll
      for (int jt = 0; jt < 4; jt++)
#pragma unroll
        for (int r = 0; r < 4; r++){
          const float pv = __expf(S[i][jt][r] - mnew[r]);
          const u16 pq = f2bf_rne(pv);
          psum[r] += bf2f(pq);
          pw[(i * 16 + q4 * 4 + r) * 72 + jt * 16 + m16] = pq;
        }
#pragma unroll
      for (int r = 0; r < 4; r++){
        float s = psum[r];
        s += __shfl_xor(s, 1); s += __shfl_xor(s, 2);
        s += __shfl_xor(s, 4); s += __shfl_xor(s, 8);
        l_run[i][r] += s;
      }
    }
    // O += P @ V   (P from per-wave LDS, V from VT columns)
#pragma unroll
    for (int ks = 0; ks < 2; ks++){
      short8 pa[3], vf[4];
#pragma unroll
      for (int i = 0; i < 3; i++)
        pa[i] = *(const short8*)(pw + (i * 16 + m16) * 72 + ks * 32 + q4 * 8);
#pragma unroll
      for (int jo = 0; jo < 4; jo++)
        vf[jo] = *(const short8*)(vt + (size_t)(jo * 16 + m16) * L_ + t0 + ks * 32 + q4 * 8);
#pragma unroll
      for (int i = 0; i < 3; i++)
#pragma unroll
        for (int jo = 0; jo < 4; jo++)
          O[i][jo] = __builtin_amdgcn_mfma_f32_16x16x32_bf16(pa[i], vf[jo], O[i][jo], 0, 0, 0);
    }
  }

  // write per-wave partial state
  const int state = (bh * CHUNKS_ + chunk) * 4 + w;
  float* mlp = MLP + (size_t)state * 48 * 2;
  float* ctxp = CTXP + (size_t)state * 48 * 64;
#pragma unroll
  for (int i = 0; i < 3; i++)
#pragma unroll
    for (int r = 0; r < 4; r++){
      const int row = i * 16 + q4 * 4 + r;
      if (m16 == 0){ mlp[row * 2] = m_run[i][r]; mlp[row * 2 + 1] = l_run[i][r]; }
#pragma unroll
      for (int jo = 0; jo < 4; jo++)
        ctxp[row * 64 + jo * 16 + m16] = O[i][jo][r];
    }
}

// ---------------- merge partials + mean over u ----------------
__global__ void attn_combine(const float* __restrict__ MLP, const float* __restrict__ CTXP,
                             float* __restrict__ CTXF){
  const int bh = blockIdx.x;
  const int b = bh >> 4, h = bh & 15;
  const int t = threadIdx.x;
  const int col = t & 63, rg = t >> 6;
  const int NS = CHUNKS_ * 4;              // 8 states
  __shared__ float ml[8 * 48 * 2];
  __shared__ float red[4][64];
  for (int i = t; i < NS * 48 * 2; i += 256) ml[i] = MLP[(size_t)bh * NS * 48 * 2 + i];
  __syncthreads();
  float acc = 0.f;
  for (int rr = 0; rr < 12; rr++){
    const int row = rg * 12 + rr;
    if (row >= U_) break;
    float M = -1e30f;
#pragma unroll
    for (int s = 0; s < NS; s++) M = fmaxf(M, ml[s * 96 + row * 2]);
    float num = 0.f, den = 0.f;
#pragma unroll
    for (int s = 0; s < NS; s++){
      const float wgt = __expf(ml[s * 96 + row * 2] - M);
      num += wgt * CTXP[((size_t)bh * NS + s) * 48 * 64 + row * 64 + col];
      den += wgt * ml[s * 96 + row * 2 + 1];
    }
    acc += num / den;
  }
  red[rg][col] = acc;
  __syncthreads();
  if (t < 64){
    const float v = (red[0][t] + red[1][t] + red[2][t] + red[3][t]) * (1.0f / 45.0f);
    CTXF[b * DM_ + t * H_ + h] = v;
  }
}

// ---------------- out[b,j] = ctx_flat[b] . Wo[j,:] + bo[j] ----------------
__global__ void s4_out(const float* __restrict__ CTXF, const float* __restrict__ Wo,
                       const float* __restrict__ bo, float* __restrict__ out){
  const int jb = blockIdx.x;   // 4
  const int b = blockIdx.y;    // 8
  const int t = threadIdx.x;
  __shared__ float cx[DM_];
  for (int i = t; i < DM_; i += 256) cx[i] = CTXF[b * DM_ + i];
  __syncthreads();
  const int j = jb * 256 + t;
  const float* wrow = Wo + (size_t)j * DM_;
  float acc = bo[j];
  for (int c = 0; c < 256; c++){
    const float4 wv = *(const float4*)(wrow + c * 4);
    const float4 cv = *(const float4*)(cx + c * 4);
    acc += wv.x * cv.x + wv.y * cv.y + wv.z * cv.z + wv.w * cv.w;
  }
  out[b * DM_ + j] = acc;
}

extern "C" void kernel_launch(void* const* d_in, const int* in_sizes, int n_in,
                              void* d_out, int out_size, void* d_ws, size_t ws_size,
                              hipStream_t stream){
  const float* Q  = (const float*)d_in[0];
  const float* K  = (const float*)d_in[1];
  const float* V  = (const float*)d_in[2];
  const float* Wq = (const float*)d_in[3];
  const float* bq = (const float*)d_in[4];
  const float* Wk = (const float*)d_in[5];
  const float* bk = (const float*)d_in[6];
  const float* Wv = (const float*)d_in[7];
  const float* bv = (const float*)d_in[8];
  const float* Wo = (const float*)d_in[9];
  const float* bo = (const float*)d_in[10];
  const int* IDX  = (const int*)d_in[11];
  float* out = (float*)d_out;

  char* p = (char*)d_ws;
  auto alloc = [&](size_t bytes) -> char* {
    char* r = p; p += (bytes + 255) & ~(size_t)255; return r;
  };
  u16*  WQH  = (u16*)alloc((size_t)DM_ * DM_ * 2);
  u16*  WQL  = (u16*)alloc((size_t)DM_ * DM_ * 2);
  u16*  WKH  = (u16*)alloc((size_t)DM_ * DM_ * 2);
  u16*  WKL  = (u16*)alloc((size_t)DM_ * DM_ * 2);
  u16*  WVH  = (u16*)alloc((size_t)DM_ * DM_ * 2);
  float* QF  = (float*)alloc((size_t)BH_ * L_ * DH_ * 4);   // 128 MiB
  u16*  KB   = (u16*)alloc((size_t)BH_ * L_ * DH_ * 2);     // 64 MiB
  u16*  VT   = (u16*)alloc((size_t)BH_ * DH_ * L_ * 2);     // 64 MiB (transposed)
  float* GATH = (float*)alloc((size_t)GM_ * DM_ * 4);       // 12 MiB
  float* KSAMP= (float*)alloc((size_t)GM_ * DM_ * 4);       // 12 MiB
  float* MBUF = (float*)alloc((size_t)BH_ * L_ * 4);        // 2 MiB
  int*   MTOP = (int*)alloc((size_t)BH_ * U_ * 4);
  float* MLP  = (float*)alloc((size_t)BH_ * CHUNKS_ * 4 * 48 * 2 * 4);
  float* CTXP = (float*)alloc((size_t)BH_ * CHUNKS_ * 4 * 48 * 64 * 4);  // 12.6 MiB
  float* CTXF = (float*)alloc((size_t)B_ * DM_ * 4);

  prep_w<<<dim3(1024), dim3(256), 0, stream>>>(Wq, Wk, Wv, WQH, WQL, WKH, WKL, WVH);
  gather_rows<<<dim3(B_ * U_), dim3(256), 0, stream>>>(K, IDX, GATH);
  gemm_proj<3, 0><<<dim3(8, 256), dim3(256), 0, stream>>>(Q, WQH, WQL, bq, (void*)QF);
  gemm_proj<1, 1><<<dim3(8, 256), dim3(256), 0, stream>>>(K, WKH, (const u16*)nullptr, bk, (void*)KB);
  gemm_proj<1, 3><<<dim3(8, 256), dim3(256), 0, stream>>>(V, WVH, (const u16*)nullptr, bv, (void*)VT);
  gemm_proj<3, 2><<<dim3(8, GM_ / 128), dim3(256), 0, stream>>>(GATH, WKH, WKL, bk, (void*)KSAMP);
  compute_m<<<dim3(BH_ * 16), dim3(256), 0, stream>>>(QF, KSAMP, MBUF);
  topk45<<<dim3(BH_), dim3(256), 0, stream>>>(MBUF, MTOP);
  attn_fused<<<dim3(BH_, CHUNKS_), dim3(256), 0, stream>>>(QF, KB, VT, MTOP, MLP, CTXP);
  attn_combine<<<dim3(BH_), dim3(256), 0, stream>>>(MLP, CTXP, CTXF);
  s4_out<<<dim3(4, 8), dim3(256), 0, stream>>>(CTXF, Wo, bo, out);
}

// Round 3
// 997.482 us; speedup vs baseline: 1.7223x; 1.1899x over previous
//
#include <hip/hip_runtime.h>
#include <stdint.h>

#define B_ 8
#define L_ 4096
#define DM_ 1024
#define H_ 16
#define DH_ 64
#define U_ 45
#define BH_ 128
#define CHUNKS_ 2

typedef unsigned short u16;
typedef unsigned int u32;
typedef __attribute__((ext_vector_type(8))) short short8;
typedef __attribute__((ext_vector_type(4))) float f32x4;

__device__ __forceinline__ u16 f2bf_rne(float x){
  u32 u = __float_as_uint(x);
  return (u16)((u + 0x7FFFu + ((u >> 16) & 1u)) >> 16);
}
__device__ __forceinline__ float bf2f(u16 v){ return __uint_as_float(((u32)v) << 16); }

// async global->LDS, 16B per lane, LDS dest = wave-uniform base + lane*16
__device__ __forceinline__ void gload_lds16(const void* g, void* l){
  auto gp = (const __attribute__((address_space(1))) u32*)(uintptr_t)g;
  auto lp = (__attribute__((address_space(3))) u32*)(u32)(uintptr_t)l;
  __builtin_amdgcn_global_load_lds(gp, lp, 16, 0, 0);
}

__device__ __forceinline__ void split1(float x, u16& h, u16& l){
  h = f2bf_rne(x);
  l = f2bf_rne(x - bf2f(h));
}

// ---------------- weight prep ----------------
__global__ void prep_w(const float* __restrict__ Wq, const float* __restrict__ Wk,
                       const float* __restrict__ Wv,
                       u16* __restrict__ WQH, u16* __restrict__ WQL,
                       u16* __restrict__ WKH, u16* __restrict__ WKL,
                       u16* __restrict__ WVH){
  const int i = (blockIdx.x * 256 + threadIdx.x) * 4;
  float4 a; ushort4 h, l;
  a = *(const float4*)(Wq + i);
  split1(a.x, h.x, l.x); split1(a.y, h.y, l.y); split1(a.z, h.z, l.z); split1(a.w, h.w, l.w);
  *(ushort4*)(WQH + i) = h; *(ushort4*)(WQL + i) = l;
  a = *(const float4*)(Wk + i);
  split1(a.x, h.x, l.x); split1(a.y, h.y, l.y); split1(a.z, h.z, l.z); split1(a.w, h.w, l.w);
  *(ushort4*)(WKH + i) = h; *(ushort4*)(WKL + i) = l;
  a = *(const float4*)(Wv + i);
  split1(a.x, h.x, l.x); split1(a.y, h.y, l.y); split1(a.z, h.z, l.z); split1(a.w, h.w, l.w);
  *(ushort4*)(WVH + i) = h;
}

// ---------------- gather sampled K rows (fp32), padded to 48 rows ----------------
__global__ void gather_rows(const float* __restrict__ K, const int* __restrict__ IDX,
                            float* __restrict__ GATH){
  const int blk = blockIdx.x;           // B_*48
  const int b = blk / 48, u = blk % 48;
  const int t = threadIdx.x;
  float4 v = make_float4(0.f, 0.f, 0.f, 0.f);
  if (u < U_){
    const int row = IDX[u];
    v = ((const float4*)(K + ((size_t)b * L_ + row) * DM_))[t];
  }
  ((float4*)(GATH + ((size_t)(b * 48 + u)) * DM_))[t] = v;
}

// ---------------- projection GEMM ----------------
// C[g,c] = sum_k A[g,k]*W[c,k] + bias[c].  A fp32 [Mx1024], W bf16 hi(/lo) [1024x1024].
// XOR-swizzled LDS staging: A (256B rows): global chunk c^(row&15) at pos c;
// B (128B rows): c^(row&7).  Frag reads recompute pos -> all 32 banks busy.
// OUTMODE 0: fp32 scatter [B,H,L,64]; 1: bf16 scatter; 2: fp32 [Mx1024];
// 3: bf16 transposed [B,H,64,L].  WITHM: fuse M=max-mean(q.k_samp) -> MBUF.
template<int PASSES, int OUTMODE, bool WITHM>
__launch_bounds__(256, 2)
__global__ void gemm_proj(const float* __restrict__ A, const u16* __restrict__ BHp,
                          const u16* __restrict__ BLp, const float* __restrict__ bias,
                          void* __restrict__ outp,
                          const u16* __restrict__ KSH, const u16* __restrict__ KSL,
                          float* __restrict__ MBUF){
  constexpr int LDSB = WITHM ? 69632 : (PASSES == 3 ? 65536 : 49152);
  __shared__ __attribute__((aligned(16))) char smem[LDSB];
  float* As = (float*)smem;                 // 32 KB (128x64 fp32)
  u16* Bhs = (u16*)(smem + 32768);          // 16 KB (128x64 u16)
  u16* Bls = (u16*)(smem + 49152);          // 16 KB (PASSES==3 only)

  const int n0 = blockIdx.x * 128;
  const int m0 = blockIdx.y * 128;
  const int t = threadIdx.x;
  const int w = t >> 6, lane = t & 63;
  const int wr = w >> 1, wc = w & 1;
  const int m16 = lane & 15, q4 = lane >> 4;

  f32x4 acc[4][4];
#pragma unroll
  for (int i = 0; i < 4; i++)
#pragma unroll
    for (int j = 0; j < 4; j++) acc[i][j] = (f32x4){0.f, 0.f, 0.f, 0.f};

  const int arow = lane >> 4;            // 0..3 (4 rows per A instr)
  const int acN  = lane & 15;            // A chunk slot
  const int brow = lane >> 3;            // 0..7 (8 rows per B instr)
  const int bcN  = lane & 7;             // B chunk slot

  for (int kt = 0; kt < 16; kt++){
    const int k0 = kt * 64;
    // stage A fp32 128x64 : 32 instrs x 1024B, swizzled chunk
#pragma unroll
    for (int ii = 0; ii < 8; ii++){
      const int nn = w * 8 + ii;
      const int rl = 4 * nn + arow;
      const int c2 = acN ^ (rl & 15);
      const float* gp = A + (size_t)(m0 + rl) * DM_ + (k0 + c2 * 4);
      gload_lds16(gp, As + nn * 256);
    }
    // stage B bf16 128x64 : 16 instrs x 1024B, swizzled chunk
#pragma unroll
    for (int ii = 0; ii < 4; ii++){
      const int nn = w * 4 + ii;
      const int rb = 8 * nn + brow;
      const int cb = bcN ^ (brow & 7);
      const size_t go = (size_t)(n0 + rb) * DM_ + (k0 + cb * 8);
      gload_lds16(BHp + go, Bhs + nn * 512);
      if constexpr (PASSES == 3) gload_lds16(BLp + go, Bls + nn * 512);
    }
    __syncthreads();

#pragma unroll
    for (int ks = 0; ks < 2; ks++){
      const int gc0 = ks * 8 + q4 * 2;     // fp32 16B-chunk pair
      short8 ah[4], al[4];
#pragma unroll
      for (int i = 0; i < 4; i++){
        const float* base = As + (wr * 64 + i * 16 + m16) * 64;
        const f32x4 xlo = *(const f32x4*)(base + (gc0 ^ m16) * 4);
        const f32x4 xhi = *(const f32x4*)(base + ((gc0 + 1) ^ m16) * 4);
        float xx[8] = {xlo[0], xlo[1], xlo[2], xlo[3], xhi[0], xhi[1], xhi[2], xhi[3]};
        short8 h, l;
#pragma unroll
        for (int c = 0; c < 8; c++){
          const u32 ub = __float_as_uint(xx[c]);
          h[c] = (short)(ub >> 16);
          if constexpr (PASSES == 3){
            const float r = xx[c] - __uint_as_float(ub & 0xFFFF0000u);
            l[c] = (short)(__float_as_uint(r) >> 16);
          }
        }
        ah[i] = h;
        if constexpr (PASSES == 3) al[i] = l;
      }
      const int gcb = ks * 4 + q4;         // bf16 16B chunk
      short8 bh8[4], bl8[4];
#pragma unroll
      for (int j = 0; j < 4; j++){
        const int rowb = wc * 64 + j * 16 + m16;
        const int pos = gcb ^ (m16 & 7);
        bh8[j] = *(const short8*)(Bhs + rowb * 64 + pos * 8);
        if constexpr (PASSES == 3) bl8[j] = *(const short8*)(Bls + rowb * 64 + pos * 8);
      }
#pragma unroll
      for (int i = 0; i < 4; i++)
#pragma unroll
        for (int j = 0; j < 4; j++){
          acc[i][j] = __builtin_amdgcn_mfma_f32_16x16x32_bf16(ah[i], bh8[j], acc[i][j], 0, 0, 0);
          if constexpr (PASSES == 3){
            acc[i][j] = __builtin_amdgcn_mfma_f32_16x16x32_bf16(ah[i], bl8[j], acc[i][j], 0, 0, 0);
            acc[i][j] = __builtin_amdgcn_mfma_f32_16x16x32_bf16(al[i], bh8[j], acc[i][j], 0, 0, 0);
          }
        }
    }
    __syncthreads();
  }

  // epilogue: C/D layout col=lane&15, row=(lane>>4)*4+reg  [verified m89/m91]
  float* mt = (float*)smem + w * (64 * 68);   // per-wave 64x68 fp32 (WITHM)
  if constexpr (OUTMODE == 3){
    u16* tb = (u16*)smem;                  // 64 x 136 u16, reuses staging LDS
    const int b = m0 >> 12;
    const int l0 = m0 & 4095;
#pragma unroll
    for (int p = 0; p < 2; p++){
      if (wc == p){
#pragma unroll
        for (int j = 0; j < 4; j++){
          const int cl = j * 16 + m16;
          const float bv = bias[n0 + p * 64 + cl];
#pragma unroll
          for (int i = 0; i < 4; i++){
#pragma unroll
            for (int r = 0; r < 4; r++){
              const int gl = wr * 64 + i * 16 + q4 * 4 + r;
              tb[cl * 136 + gl] = f2bf_rne(acc[i][j][r] + bv);
            }
          }
        }
      }
      __syncthreads();
      {
        const int cl = t >> 2;                    // 0..63
        const int c = n0 + p * 64 + cl;
        const int h = c >> 6, d = c & 63;
        u16* dst = (u16*)outp + ((size_t)((b * H_ + h) * DH_ + d)) * L_ + l0;
#pragma unroll
        for (int k = 0; k < 4; k++){
          const int ch = (t & 3) + k * 4;
          *(short8*)(dst + ch * 8) = *(const short8*)(tb + cl * 136 + ch * 8);
        }
      }
      __syncthreads();
    }
  } else {
#pragma unroll
    for (int j = 0; j < 4; j++){
      const int c = n0 + wc * 64 + j * 16 + m16;
      const float bv = bias[c];
#pragma unroll
      for (int i = 0; i < 4; i++){
        const int mb = m0 + wr * 64 + i * 16 + q4 * 4;
#pragma unroll
        for (int r = 0; r < 4; r++){
          const int g = mb + r;
          const float val = acc[i][j][r] + bv;
          if constexpr (OUTMODE == 2){
            ((float*)outp)[(size_t)g * DM_ + c] = val;
          } else {
            const int b = g >> 12, l2 = g & 4095;
            const int h = c >> 6, d = c & 63;
            const size_t oi = (((size_t)(b * H_ + h)) * L_ + l2) * DH_ + d;
            if constexpr (OUTMODE == 0) ((float*)outp)[oi] = val;
            else ((u16*)outp)[oi] = (u16)(__float_as_uint(val) >> 16);
          }
          if constexpr (WITHM)
            mt[(i * 16 + q4 * 4 + r) * 68 + (j * 16 + m16)] = val;
        }
      }
    }
  }

  if constexpr (WITHM){
    // per-wave: qk = (64 q rows) x (48 k_samp rows), 3-pass bf16, then M=max-mean
    const int bb = m0 >> 12;
    const int head = (n0 >> 6) + wc;
    const int bh2 = bb * H_ + head;
    f32x4 S[4][3];
#pragma unroll
    for (int im = 0; im < 4; im++)
#pragma unroll
      for (int jt = 0; jt < 3; jt++) S[im][jt] = (f32x4){0.f, 0.f, 0.f, 0.f};
#pragma unroll
    for (int ks = 0; ks < 2; ks++){
      short8 kh3[3], kl3[3];
#pragma unroll
      for (int jt = 0; jt < 3; jt++){
        const size_t ko = ((size_t)bh2 * 48 + jt * 16 + m16) * 64 + ks * 32 + q4 * 8;
        kh3[jt] = *(const short8*)(KSH + ko);
        kl3[jt] = *(const short8*)(KSL + ko);
      }
#pragma unroll
      for (int im = 0; im < 4; im++){
        const float* ap = mt + (im * 16 + m16) * 68 + ks * 32 + q4 * 8;
        const f32x4 xlo = *(const f32x4*)ap;
        const f32x4 xhi = *(const f32x4*)(ap + 4);
        float xx[8] = {xlo[0], xlo[1], xlo[2], xlo[3], xhi[0], xhi[1], xhi[2], xhi[3]};
        short8 qh, ql;
#pragma unroll
        for (int c = 0; c < 8; c++){
          const u32 ub = __float_as_uint(xx[c]);
          qh[c] = (short)(ub >> 16);
          const float r = xx[c] - __uint_as_float(ub & 0xFFFF0000u);
          ql[c] = (short)(__float_as_uint(r) >> 16);
        }
#pragma unroll
        for (int jt = 0; jt < 3; jt++){
          S[im][jt] = __builtin_amdgcn_mfma_f32_16x16x32_bf16(qh, kh3[jt], S[im][jt], 0, 0, 0);
          S[im][jt] = __builtin_amdgcn_mfma_f32_16x16x32_bf16(qh, kl3[jt], S[im][jt], 0, 0, 0);
          S[im][jt] = __builtin_amdgcn_mfma_f32_16x16x32_bf16(ql, kh3[jt], S[im][jt], 0, 0, 0);
        }
      }
    }
#pragma unroll
    for (int im = 0; im < 4; im++)
#pragma unroll
      for (int r = 0; r < 4; r++){
        float mx = -1e30f, sm = 0.f;
#pragma unroll
        for (int jt = 0; jt < 3; jt++){
          const bool ok = (jt < 2) || (m16 < 13);   // u = jt*16+m16 < 45
          const float v = S[im][jt][r];
          if (ok){ mx = fmaxf(mx, v); sm += v; }
        }
#pragma unroll
        for (int off = 1; off < 16; off <<= 1){
          mx = fmaxf(mx, __shfl_xor(mx, off));
          sm += __shfl_xor(sm, off);
        }
        if (m16 == 0){
          const int l2 = (m0 & 4095) + wr * 64 + im * 16 + q4 * 4 + r;
          MBUF[(size_t)bh2 * L_ + l2] = mx - sm * (1.0f / 45.0f);
        }
      }
  }
}

// ---------------- k_samp hi/lo prep: KSAMP fp32 [B*48 x 1024] -> [bh][48][64] ----------------
__global__ void ksprep(const float* __restrict__ KSAMP, u16* __restrict__ KSH,
                       u16* __restrict__ KSL){
  const int bh = blockIdx.x;
  const int b = bh >> 4, h = bh & 15;
  const int t = threadIdx.x;
  for (int i = t; i < 48 * 64; i += 256){
    const int u = i >> 6, d = i & 63;
    const float v = (u < U_) ? KSAMP[(size_t)(b * 48 + u) * DM_ + h * DH_ + d] : 0.f;
    u16 hh, ll; split1(v, hh, ll);
    KSH[(size_t)bh * 48 * 64 + i] = hh;
    KSL[(size_t)bh * 48 * 64 + i] = ll;
  }
}

// ---------------- iterative top-45, conflict-free + shfl reduce ----------------
__global__ void topk45(const float* __restrict__ MBUF, int* __restrict__ MTOP){
  const int bh = blockIdx.x;
  const int t = threadIdx.x, w = t >> 6, lane = t & 63;
  __shared__ float Mv[L_];
  __shared__ float rv[4];
  __shared__ int ri[4];
  for (int i = t; i < L_; i += 256) Mv[i] = MBUF[(size_t)bh * L_ + i];
  __syncthreads();
  for (int it = 0; it < U_; it++){
    float bv = -1e30f; int bi = 0;
#pragma unroll
    for (int c = 0; c < 16; c++){
      const int idx = c * 256 + t;          // consecutive t -> conflict-free
      const float v = Mv[idx];
      if (v > bv || (v == bv && idx < bi)){ bv = v; bi = idx; }
    }
#pragma unroll
    for (int off = 1; off < 64; off <<= 1){
      const float ov = __shfl_xor(bv, off);
      const int oi = __shfl_xor(bi, off);
      if (ov > bv || (ov == bv && oi < bi)){ bv = ov; bi = oi; }
    }
    if (lane == 0){ rv[w] = bv; ri[w] = bi; }
    __syncthreads();
    if (t == 0){
      float fb = rv[0]; int fi = ri[0];
#pragma unroll
      for (int s = 1; s < 4; s++)
        if (rv[s] > fb || (rv[s] == fb && ri[s] < fi)){ fb = rv[s]; fi = ri[s]; }
      MTOP[bh * U_ + it] = fi;
      Mv[fi] = -1e30f;
    }
    __syncthreads();
  }
}

// ---------------- fused flash-style attention (MFMA) ----------------
__launch_bounds__(256, 2)
__global__ void attn_fused(const float* __restrict__ QF, const u16* __restrict__ KB,
                           const u16* __restrict__ VT, const int* __restrict__ MTOP,
                           float* __restrict__ MLP, float* __restrict__ CTXP){
  const int bh = blockIdx.x;
  const int chunk = blockIdx.y;
  const int t = threadIdx.x, w = t >> 6, lane = t & 63;
  const int m16 = lane & 15, q4 = lane >> 4;

  __shared__ __attribute__((aligned(16))) float qs[48 * 68];
  __shared__ __attribute__((aligned(16))) u16 ps[4][48 * 72];

  for (int i = t; i < 48 * 64; i += 256){
    const int r = i >> 6, d = i & 63;
    float v = 0.f;
    if (r < U_) v = QF[((size_t)bh * L_ + MTOP[bh * U_ + r]) * DH_ + d] * 0.125f;
    qs[r * 68 + d] = v;
  }
  __syncthreads();

  short8 qh[3][2], ql[3][2];
#pragma unroll
  for (int i = 0; i < 3; i++)
#pragma unroll
    for (int ks = 0; ks < 2; ks++){
      const float* ap = qs + (i * 16 + m16) * 68 + ks * 32 + q4 * 8;
      const f32x4 xlo = *(const f32x4*)ap;
      const f32x4 xhi = *(const f32x4*)(ap + 4);
      float xx[8] = {xlo[0], xlo[1], xlo[2], xlo[3], xhi[0], xhi[1], xhi[2], xhi[3]};
      short8 h, l;
#pragma unroll
      for (int c = 0; c < 8; c++){
        const u32 ub = __float_as_uint(xx[c]);
        h[c] = (short)(ub >> 16);
        const float r = xx[c] - __uint_as_float(ub & 0xFFFF0000u);
        l[c] = (short)(__float_as_uint(r) >> 16);
      }
      qh[i][ks] = h; ql[i][ks] = l;
    }

  float m_run[3][4], l_run[3][4];
  f32x4 O[3][4];
#pragma unroll
  for (int i = 0; i < 3; i++)
#pragma unroll
    for (int r = 0; r < 4; r++){
      m_run[i][r] = -1e30f; l_run[i][r] = 0.f;
      O[i][r] = (f32x4){0.f, 0.f, 0.f, 0.f};
    }

  const u16* kb = KB + (size_t)bh * L_ * DH_;
  const u16* vt = VT + (size_t)bh * DH_ * L_;
  const int TPW = L_ / (CHUNKS_ * 4 * 64);
  u16* pw = ps[w];

  for (int tt = 0; tt < TPW; tt++){
    const int t0 = ((chunk * 4 + w) * TPW + tt) * 64;
    f32x4 S[3][4];
#pragma unroll
    for (int i = 0; i < 3; i++)
#pragma unroll
      for (int jt = 0; jt < 4; jt++) S[i][jt] = (f32x4){0.f, 0.f, 0.f, 0.f};
#pragma unroll
    for (int ks = 0; ks < 2; ks++){
      short8 kf[4];
#pragma unroll
      for (int jt = 0; jt < 4; jt++)
        kf[jt] = *(const short8*)(kb + (size_t)(t0 + jt * 16 + m16) * DH_ + ks * 32 + q4 * 8);
#pragma unroll
      for (int i = 0; i < 3; i++)
#pragma unroll
        for (int jt = 0; jt < 4; jt++){
          S[i][jt] = __builtin_amdgcn_mfma_f32_16x16x32_bf16(qh[i][ks], kf[jt], S[i][jt], 0, 0, 0);
          S[i][jt] = __builtin_amdgcn_mfma_f32_16x16x32_bf16(ql[i][ks], kf[jt], S[i][jt], 0, 0, 0);
        }
    }
#pragma unroll
    for (int i = 0; i < 3; i++){
      float mnew[4], alpha[4], psum[4];
#pragma unroll
      for (int r = 0; r < 4; r++){
        float mx = fmaxf(fmaxf(S[i][0][r], S[i][1][r]), fmaxf(S[i][2][r], S[i][3][r]));
        mx = fmaxf(mx, __shfl_xor(mx, 1));
        mx = fmaxf(mx, __shfl_xor(mx, 2));
        mx = fmaxf(mx, __shfl_xor(mx, 4));
        mx = fmaxf(mx, __shfl_xor(mx, 8));
        mnew[r] = fmaxf(m_run[i][r], mx);
        alpha[r] = __expf(m_run[i][r] - mnew[r]);
        m_run[i][r] = mnew[r];
        l_run[i][r] *= alpha[r];
        psum[r] = 0.f;
      }
#pragma unroll
      for (int jo = 0; jo < 4; jo++)
#pragma unroll
        for (int r = 0; r < 4; r++) O[i][jo][r] *= alpha[r];
#pragma unroll
      for (int jt = 0; jt < 4; jt++)
#pragma unroll
        for (int r = 0; r < 4; r++){
          const float pv = __expf(S[i][jt][r] - mnew[r]);
          const u16 pq = f2bf_rne(pv);
          psum[r] += bf2f(pq);
          pw[(i * 16 + q4 * 4 + r) * 72 + jt * 16 + m16] = pq;
        }
#pragma unroll
      for (int r = 0; r < 4; r++){
        float s = psum[r];
        s += __shfl_xor(s, 1); s += __shfl_xor(s, 2);
        s += __shfl_xor(s, 4); s += __shfl_xor(s, 8);
        l_run[i][r] += s;
      }
    }
#pragma unroll
    for (int ks = 0; ks < 2; ks++){
      short8 pa[3], vf[4];
#pragma unroll
      for (int i = 0; i < 3; i++)
        pa[i] = *(const short8*)(pw + (i * 16 + m16) * 72 + ks * 32 + q4 * 8);
#pragma unroll
      for (int jo = 0; jo < 4; jo++)
        vf[jo] = *(const short8*)(vt + (size_t)(jo * 16 + m16) * L_ + t0 + ks * 32 + q4 * 8);
#pragma unroll
      for (int i = 0; i < 3; i++)
#pragma unroll
        for (int jo = 0; jo < 4; jo++)
          O[i][jo] = __builtin_amdgcn_mfma_f32_16x16x32_bf16(pa[i], vf[jo], O[i][jo], 0, 0, 0);
    }
  }

  const int state = (bh * CHUNKS_ + chunk) * 4 + w;
  float* mlp = MLP + (size_t)state * 48 * 2;
  float* ctxp = CTXP + (size_t)state * 48 * 64;
#pragma unroll
  for (int i = 0; i < 3; i++)
#pragma unroll
    for (int r = 0; r < 4; r++){
      const int row = i * 16 + q4 * 4 + r;
      if (m16 == 0){ mlp[row * 2] = m_run[i][r]; mlp[row * 2 + 1] = l_run[i][r]; }
#pragma unroll
      for (int jo = 0; jo < 4; jo++)
        ctxp[row * 64 + jo * 16 + m16] = O[i][jo][r];
    }
}

// ---------------- merge partials + mean over u ----------------
__global__ void attn_combine(const float* __restrict__ MLP, const float* __restrict__ CTXP,
                             float* __restrict__ CTXF){
  const int bh = blockIdx.x;
  const int b = bh >> 4, h = bh & 15;
  const int t = threadIdx.x;
  const int col = t & 63, rg = t >> 6;
  const int NS = CHUNKS_ * 4;
  __shared__ float ml[8 * 48 * 2];
  __shared__ float red[4][64];
  for (int i = t; i < NS * 48 * 2; i += 256) ml[i] = MLP[(size_t)bh * NS * 48 * 2 + i];
  __syncthreads();
  float acc = 0.f;
  for (int rr = 0; rr < 12; rr++){
    const int row = rg * 12 + rr;
    if (row >= U_) break;
    float M = -1e30f;
#pragma unroll
    for (int s = 0; s < NS; s++) M = fmaxf(M, ml[s * 96 + row * 2]);
    float num = 0.f, den = 0.f;
#pragma unroll
    for (int s = 0; s < NS; s++){
      const float wgt = __expf(ml[s * 96 + row * 2] - M);
      num += wgt * CTXP[((size_t)bh * NS + s) * 48 * 64 + row * 64 + col];
      den += wgt * ml[s * 96 + row * 2 + 1];
    }
    acc += num / den;
  }
  red[rg][col] = acc;
  __syncthreads();
  if (t < 64){
    const float v = (red[0][t] + red[1][t] + red[2][t] + red[3][t]) * (1.0f / 45.0f);
    CTXF[b * DM_ + t * H_ + h] = v;
  }
}

// ---------------- out[b,j] = ctx_flat[b] . Wo[j,:] + bo[j] ----------------
__global__ void s4_out(const float* __restrict__ CTXF, const float* __restrict__ Wo,
                       const float* __restrict__ bo, float* __restrict__ out){
  const int jb = blockIdx.x;
  const int b = blockIdx.y;
  const int t = threadIdx.x;
  __shared__ float cx[DM_];
  for (int i = t; i < DM_; i += 256) cx[i] = CTXF[b * DM_ + i];
  __syncthreads();
  const int j = jb * 256 + t;
  const float* wrow = Wo + (size_t)j * DM_;
  float acc = bo[j];
  for (int c = 0; c < 256; c++){
    const float4 wv = *(const float4*)(wrow + c * 4);
    const float4 cv = *(const float4*)(cx + c * 4);
    acc += wv.x * cv.x + wv.y * cv.y + wv.z * cv.z + wv.w * cv.w;
  }
  out[b * DM_ + j] = acc;
}

extern "C" void kernel_launch(void* const* d_in, const int* in_sizes, int n_in,
                              void* d_out, int out_size, void* d_ws, size_t ws_size,
                              hipStream_t stream){
  const float* Q  = (const float*)d_in[0];
  const float* K  = (const float*)d_in[1];
  const float* V  = (const float*)d_in[2];
  const float* Wq = (const float*)d_in[3];
  const float* bq = (const float*)d_in[4];
  const float* Wk = (const float*)d_in[5];
  const float* bk = (const float*)d_in[6];
  const float* Wv = (const float*)d_in[7];
  const float* bv = (const float*)d_in[8];
  const float* Wo = (const float*)d_in[9];
  const float* bo = (const float*)d_in[10];
  const int* IDX  = (const int*)d_in[11];
  float* out = (float*)d_out;

  char* p = (char*)d_ws;
  auto alloc = [&](size_t bytes) -> char* {
    char* r = p; p += (bytes + 255) & ~(size_t)255; return r;
  };
  u16*  WQH  = (u16*)alloc((size_t)DM_ * DM_ * 2);
  u16*  WQL  = (u16*)alloc((size_t)DM_ * DM_ * 2);
  u16*  WKH  = (u16*)alloc((size_t)DM_ * DM_ * 2);
  u16*  WKL  = (u16*)alloc((size_t)DM_ * DM_ * 2);
  u16*  WVH  = (u16*)alloc((size_t)DM_ * DM_ * 2);
  float* QF  = (float*)alloc((size_t)BH_ * L_ * DH_ * 4);   // 128 MiB
  u16*  KB   = (u16*)alloc((size_t)BH_ * L_ * DH_ * 2);     // 64 MiB
  u16*  VT   = (u16*)alloc((size_t)BH_ * DH_ * L_ * 2);     // 64 MiB
  float* GATH = (float*)alloc((size_t)B_ * 48 * DM_ * 4);   // 1.5 MiB
  float* KSAMP= (float*)alloc((size_t)B_ * 48 * DM_ * 4);   // 1.5 MiB
  u16*  KSH  = (u16*)alloc((size_t)BH_ * 48 * DH_ * 2);
  u16*  KSL  = (u16*)alloc((size_t)BH_ * 48 * DH_ * 2);
  float* MBUF = (float*)alloc((size_t)BH_ * L_ * 4);        // 2 MiB
  int*   MTOP = (int*)alloc((size_t)BH_ * U_ * 4);
  float* MLP  = (float*)alloc((size_t)BH_ * CHUNKS_ * 4 * 48 * 2 * 4);
  float* CTXP = (float*)alloc((size_t)BH_ * CHUNKS_ * 4 * 48 * 64 * 4);
  float* CTXF = (float*)alloc((size_t)B_ * DM_ * 4);

  prep_w<<<dim3(1024), dim3(256), 0, stream>>>(Wq, Wk, Wv, WQH, WQL, WKH, WKL, WVH);
  gather_rows<<<dim3(B_ * 48), dim3(256), 0, stream>>>(K, IDX, GATH);
  gemm_proj<3, 2, false><<<dim3(8, 3), dim3(256), 0, stream>>>(
      GATH, WKH, WKL, bk, (void*)KSAMP, nullptr, nullptr, nullptr);
  ksprep<<<dim3(BH_), dim3(256), 0, stream>>>(KSAMP, KSH, KSL);
  gemm_proj<3, 0, true><<<dim3(8, 256), dim3(256), 0, stream>>>(
      Q, WQH, WQL, bq, (void*)QF, KSH, KSL, MBUF);
  gemm_proj<1, 1, false><<<dim3(8, 256), dim3(256), 0, stream>>>(
      K, WKH, nullptr, bk, (void*)KB, nullptr, nullptr, nullptr);
  gemm_proj<1, 3, false><<<dim3(8, 256), dim3(256), 0, stream>>>(
      V, WVH, nullptr, bv, (void*)VT, nullptr, nullptr, nullptr);
  topk45<<<dim3(BH_), dim3(256), 0, stream>>>(MBUF, MTOP);
  attn_fused<<<dim3(BH_, CHUNKS_), dim3(256), 0, stream>>>(QF, KB, VT, MTOP, MLP, CTXP);
  attn_combine<<<dim3(BH_), dim3(256), 0, stream>>>(MLP, CTXP, CTXF);
  s4_out<<<dim3(4, 8), dim3(256), 0, stream>>>(CTXF, Wo, bo, out);
}